// Round 15
// baseline (863.239 us; speedup 1.0000x reference)
//
#include <hip/hip_runtime.h>
#include <math.h>

// CapsuleLayer dynamic routing, MI355X.
// B=4096, L=200, Din=Dout=64, K=8, 3 iterations.
//
// R14 -> R15: R14 (reg-retained delta) won but sits latency-bound at 40%
// occupancy: v[13] parked in AGPRs counts against the unified 512-reg file
// (~128/thread) -> 4 waves/EU. Fix: (a) __launch_bounds__(256,6) (cap 85);
// (b) shed 32 regs by reading hs from LDS per use (b128 broadcast, 2-way,
// free) instead of an hs4[8] register stage. Peak live ~84 <= 85.
//
// ws layout (floats): St[4096] | Wt[200*1600 (s,l,k)] | Bc[1600] | partial[B*K*L]
// p2[16*1600] lives in d_out (overwritten by the final route pass).

#define B_SZ  4096
#define L_SZ  200
#define DK    64
#define K_SZ  8
#define KL    1600

// ---------------- table kernel: one block per seq-len s = blockIdx+1.
// INIT=1: Bv = Bm; block 200 does the St transpose. INIT=0: Bv = BcIn+sum p2.
template<int INIT, int WRITE_BC>
__global__ __launch_bounds__(256) void k_table(const float* __restrict__ Bm,
                                               const float* __restrict__ S,
                                               const float* __restrict__ p2,
                                               const float* __restrict__ BcIn,
                                               float* __restrict__ BcOut,
                                               float* __restrict__ St,
                                               float* __restrict__ Wt) {
    int t = threadIdx.x;
    int blk = blockIdx.x;
    if (INIT && blk == 200) {          // St[o][i] = S[i][o]
        for (int j = t; j < DK * DK; j += 256) {
            int o = j >> 6, ii = j & 63;
            St[j] = S[ii * DK + o];
        }
        return;
    }
    __shared__ float Bv[KL];           // k-major: Bv[k*200+l]
    __shared__ float mArr[K_SZ], rArr[K_SZ];
    int s = blk + 1;

    for (int j = t; j < KL; j += 256) {
        float bn;
        if (INIT) {
            bn = Bm[j];
        } else {
            float acc = 0.f;
            #pragma unroll
            for (int y = 0; y < 16; ++y) acc += p2[y * KL + j];   // L2-hot
            bn = BcIn[j] + acc;
            if (WRITE_BC && blk == 0) BcOut[j] = bn;
        }
        Bv[j] = bn;
    }
    __syncthreads();

    int k = t >> 5, g = t & 31;
    const float* bk = &Bv[k * L_SZ];
    float m = -3.4e38f;
    for (int l = g; l < s; l += 32) m = fmaxf(m, bk[l]);
    #pragma unroll
    for (int st = 16; st; st >>= 1) m = fmaxf(m, __shfl_xor(m, st, 32));
    float sum = 0.f;
    for (int l = g; l < s; l += 32) sum += __expf(bk[l] - m);
    #pragma unroll
    for (int st = 16; st; st >>= 1) sum += __shfl_xor(sum, st, 32);
    if (g == 0) { mArr[k] = m; rArr[k] = 1.0f / sum; }
    __syncthreads();

    float* dst = Wt + (long)(s - 1) * KL;
    for (int j = t; j < KL; j += 256) {
        int l = j >> 3, kk = j & 7;
        dst[j] = (l < s) ? __expf(Bv[kk * L_SZ + l] - mArr[kk]) * rArr[kk] : 0.f;
    }
}

// ---------------- route: register-resident lc; delta from registers.
// grid 4096 x 256.  WRITE_OUT=1 (final iter): write squashed high, stop.
template<int WRITE_OUT>
__global__ __launch_bounds__(256, 6) void k_route7(const float* __restrict__ lc_g,
                                                   const int* __restrict__ seq_len,
                                                   const float* __restrict__ Wt_g,
                                                   const float* __restrict__ S_g,
                                                   const float* __restrict__ St_g,
                                                   float* __restrict__ partial,
                                                   float* __restrict__ out) {
    __shared__ float smem[3648];            // [0..1599]=Wl, [1600..3647]=hp_part;
                                            // delta scatter reuses [0..2303] (stride 18)
    __shared__ float hp_s[K_SZ][DK];        // 2 KB (reused as hx)
    __shared__ float hs_s[K_SZ][DK];        // 2 KB
    float* Wl = smem;
    float* hp_part = smem + 1600;           // [4][8][64]

    int t = threadIdx.x;
    int b = blockIdx.x;
    const float4* __restrict__ lc4 =
        (const float4*)(lc_g + (long)b * (L_SZ * DK));
    int sl = seq_len[b];                    // uniform

    // stage W: linear float4 copy (coalesced global, conflict-free LDS)
    {
        const float4* __restrict__ src =
            (const float4*)(Wt_g + (long)(sl - 1) * KL);
        float4* dst = (float4*)Wl;
        for (int j = t; j < KL / 4; j += 256) dst[j] = src[j];
    }
    __syncthreads();

    int grp = t >> 4;                       // row-phase 0..15
    int w = t >> 6;                         // wave

    // ---- load ALL of this thread's lc slice up front (13 loads in flight)
    float4 v[13];
    #pragma unroll
    for (int j = 0; j < 12; ++j) v[j] = lc4[t + 256 * j];
    if (t < 128) v[12] = lc4[t + 3072];
    else         v[12] = make_float4(0.f, 0.f, 0.f, 0.f);

    // ---- Phase A: hp partials from registers
    float4 a[8];
    #pragma unroll
    for (int p = 0; p < 8; ++p) a[p] = make_float4(0.f, 0.f, 0.f, 0.f);
    #pragma unroll
    for (int j = 0; j < 13; ++j) {
        int r = (j == 12) ? ((t < 128) ? 192 + grp : 199) : grp + 16 * j;
        float4 wa = *(const float4*)&Wl[r * 8];       // W[r][k=0..3]
        float4 wb = *(const float4*)&Wl[r * 8 + 4];   // W[r][k=4..7]
        float wk[8] = {wa.x, wa.y, wa.z, wa.w, wb.x, wb.y, wb.z, wb.w};
        #pragma unroll
        for (int p = 0; p < 8; ++p) {
            a[p].x = fmaf(wk[p], v[j].x, a[p].x);
            a[p].y = fmaf(wk[p], v[j].y, a[p].y);
            a[p].z = fmaf(wk[p], v[j].z, a[p].z);
            a[p].w = fmaf(wk[p], v[j].w, a[p].w);
        }
    }

    // fold 4 in-wave row-groups (butterfly ^16, ^32)
    #pragma unroll
    for (int p = 0; p < 8; ++p) {
        a[p].x += __shfl_xor(a[p].x, 16, 64);
        a[p].y += __shfl_xor(a[p].y, 16, 64);
        a[p].z += __shfl_xor(a[p].z, 16, 64);
        a[p].w += __shfl_xor(a[p].w, 16, 64);
        a[p].x += __shfl_xor(a[p].x, 32, 64);
        a[p].y += __shfl_xor(a[p].y, 32, 64);
        a[p].z += __shfl_xor(a[p].z, 32, 64);
        a[p].w += __shfl_xor(a[p].w, 32, 64);
    }
    if ((t & 63) < 16) {
        int c0 = (t & 15) * 4;
        #pragma unroll
        for (int p = 0; p < 8; ++p)
            *(float4*)&hp_part[w * 512 + p * 64 + c0] = a[p];
    }
    __syncthreads();

    // reduce 4 wave-partials -> hp_s
    {
        int kk = t >> 5, ii = (t & 31) * 2;
        float2 r2 = make_float2(0.f, 0.f);
        #pragma unroll
        for (int ww = 0; ww < 4; ++ww) {
            float2 p = *(const float2*)&hp_part[ww * 512 + kk * 64 + ii];
            r2.x += p.x; r2.y += p.y;
        }
        *(float2*)&hp_s[kk][ii] = r2;
    }
    __syncthreads();

    // high[k][o] = sum_i hp[k][i]*S[i][o]; squash.  warp k, o=2g,2g+1
    int k = t >> 5, g = t & 31;
    float h0 = 0.f, h1 = 0.f;
    {
        const float* sp = S_g + 2 * g;
        #pragma unroll 8
        for (int i = 0; i < DK; ++i) {
            float pv = hp_s[k][i];                        // broadcast
            float2 sv = *(const float2*)(sp + i * DK);    // L1-hot, coalesced
            h0 = fmaf(pv, sv.x, h0); h1 = fmaf(pv, sv.y, h1);
        }
        float nn = h0 * h0 + h1 * h1;
        #pragma unroll
        for (int st = 16; st; st >>= 1) nn += __shfl_xor(nn, st, 32);
        float sc = nn / ((1.0f + nn) * sqrtf(nn + 1e-9f));
        h0 *= sc; h1 *= sc;
    }
    if (WRITE_OUT) {
        float2* ob2 = (float2*)(out + (long)b * (K_SZ * DK) + k * DK);
        ob2[g] = make_float2(h0, h1);
        return;                              // uniform early exit
    }
    *(float2*)&hp_s[k][2 * g] = make_float2(h0, h1);  // reuse as hx: same-warp RW

    // hs[k][i] = sum_o high[k][o]*St[o][i]   warp k, i=2g,2g+1
    {
        float s0 = 0.f, s1 = 0.f;
        const float* stp = St_g + 2 * g;
        #pragma unroll 8
        for (int o = 0; o < DK; ++o) {
            float hv = hp_s[k][o];                        // same-warp broadcast
            float2 sv = *(const float2*)(stp + o * DK);   // L1-hot, coalesced
            s0 = fmaf(hv, sv.x, s0); s1 = fmaf(hv, sv.y, s1);
        }
        *(float2*)&hs_s[k][2 * g] = make_float2(s0, s1);
    }
    __syncthreads();

    // ---- delta from registers: thread t holds rows grp+16j, cols c0..c0+3.
    //      hs read from LDS per use (b128 broadcast, 2-way banks): -32 VGPR.
    int c0 = 4 * (t & 15);
    float* pb = partial + (long)b * KL;
    int lane16 = t & 15;
    #pragma unroll
    for (int j = 0; j < 13; ++j) {
        if (j < 12 || t < 128) {                   // valid rows only
            #pragma unroll
            for (int kk = 0; kk < 8; ++kk) {
                float4 h = *(const float4*)&hs_s[kk][c0];  // 2-way bcast, free
                float p = v[j].x * h.x + v[j].y * h.y + v[j].z * h.z + v[j].w * h.w;
                smem[(grp * 8 + kk) * 18 + lane16] = p;   // <=2-way banks
            }
        }
        __syncthreads();
        int nOut = (j < 12) ? 128 : 64;
        if (t < nOut) {
            int s = t >> 3, kk = t & 7;            // s = row slot
            int r = 16 * j + s;
            const float2* q = (const float2*)&smem[(s * 8 + kk) * 18];
            float2 q0 = q[0], q1 = q[1], q2 = q[2], q3 = q[3];
            float2 q4 = q[4], q5 = q[5], q6 = q[6], q7 = q[7];
            float sum = ((q0.x + q0.y) + (q1.x + q1.y))
                      + ((q2.x + q2.y) + (q3.x + q3.y))
                      + ((q4.x + q4.y) + (q5.x + q5.y))
                      + ((q6.x + q6.y) + (q7.x + q7.y));
            pb[kk * L_SZ + r] = sum;
        }
        __syncthreads();
    }
}

// --------------------------- stage-A reduce of partials (unchanged)
__global__ __launch_bounds__(256) void k_reduceA(const float* __restrict__ partial,
                                                 float* __restrict__ partial2) {
    __shared__ float red[256];
    int x = blockIdx.x % 50;
    int y = blockIdx.x / 50;
    int t = threadIdx.x;
    int i = x * 32 + (t & 31);
    int sub = t >> 5;
    float s = 0.f;
    for (int p = y * 256 + sub; p < (y + 1) * 256; p += 8)
        s += partial[(long)p * KL + i];
    red[t] = s;
    __syncthreads();
    for (int step = 4; step >= 1; step >>= 1) {
        if (sub < step) red[t] += red[t + step * 32];
        __syncthreads();
    }
    if (sub == 0) partial2[y * KL + i] = red[t];
}

extern "C" void kernel_launch(void* const* d_in, const int* in_sizes, int n_in,
                              void* d_out, int out_size, void* d_ws, size_t ws_size,
                              hipStream_t stream) {
    const float* lc = (const float*)d_in[0];   // [4096,200,64]
    const int*   sl = (const int*)d_in[1];     // [4096,1]
    const float* Bm = (const float*)d_in[2];   // [1,8,200]
    const float* S  = (const float*)d_in[3];   // [64,64]
    float* out = (float*)d_out;                // [4096,8,64]
    float* ws  = (float*)d_ws;

    float* St      = ws;                       // 4,096
    float* Wt      = St + 4096;                // 320,000  (s,l,k)
    float* Bc      = Wt + 200 * KL;            // 1,600
    float* partial = Bc + KL;                  // 6,553,600
    float* p2      = out;                      // 25,600: overwritten by final pass

    // 8 launches total.
    k_table<1,0><<<201, 256, 0, stream>>>(Bm, S, p2, Bm, Bc, St, Wt);

    k_route7<0><<<B_SZ, 256, 0, stream>>>(lc, sl, Wt, S, St, partial, out);
    k_reduceA  <<<800, 256, 0, stream>>>(partial, p2);
    k_table<0,1><<<200, 256, 0, stream>>>(Bm, S, p2, /*BcIn=*/Bm, /*BcOut=*/Bc, St, Wt);

    k_route7<0><<<B_SZ, 256, 0, stream>>>(lc, sl, Wt, S, St, partial, out);
    k_reduceA  <<<800, 256, 0, stream>>>(partial, p2);
    k_table<0,0><<<200, 256, 0, stream>>>(Bm, S, p2, /*BcIn=*/Bc, /*BcOut=*/Bc, St, Wt);

    k_route7<1><<<B_SZ, 256, 0, stream>>>(lc, sl, Wt, S, St, partial, out);
}

// Round 16
// 621.607 us; speedup vs baseline: 1.3887x; 1.3887x over previous
//
#include <hip/hip_runtime.h>
#include <math.h>

// CapsuleLayer dynamic routing, MI355X.
// B=4096, L=200, Din=Dout=64, K=8, 3 iterations.
//
// R15 -> R16: R15's (256,6) cap=85 < ~116-reg demand -> v[13] spilled to
// scratch in the hot loops (WRITE_SIZE 58->590MB, 863us). Fix demand first:
// two-pass phase A over k-halves (a[4] not a[8]: peak live ~90), THEN raise
// occupancy moderately with (256,5) (cap 102, margin ~12). Delta scatter
// does 2 row-groups per barrier round (26 -> 14 barriers). hs read from LDS
// per use (R15's one good change). Everything else = R14.
//
// ws layout (floats): St[4096] | Wt[200*1600 (s,l,k)] | Bc[1600] | partial[B*K*L]
// p2[16*1600] lives in d_out (overwritten by the final route pass).

#define B_SZ  4096
#define L_SZ  200
#define DK    64
#define K_SZ  8
#define KL    1600

// ---------------- table kernel: one block per seq-len s = blockIdx+1.
// INIT=1: Bv = Bm; block 200 does the St transpose. INIT=0: Bv = BcIn+sum p2.
template<int INIT, int WRITE_BC>
__global__ __launch_bounds__(256) void k_table(const float* __restrict__ Bm,
                                               const float* __restrict__ S,
                                               const float* __restrict__ p2,
                                               const float* __restrict__ BcIn,
                                               float* __restrict__ BcOut,
                                               float* __restrict__ St,
                                               float* __restrict__ Wt) {
    int t = threadIdx.x;
    int blk = blockIdx.x;
    if (INIT && blk == 200) {          // St[o][i] = S[i][o]
        for (int j = t; j < DK * DK; j += 256) {
            int o = j >> 6, ii = j & 63;
            St[j] = S[ii * DK + o];
        }
        return;
    }
    __shared__ float Bv[KL];           // k-major: Bv[k*200+l]
    __shared__ float mArr[K_SZ], rArr[K_SZ];
    int s = blk + 1;

    for (int j = t; j < KL; j += 256) {
        float bn;
        if (INIT) {
            bn = Bm[j];
        } else {
            float acc = 0.f;
            #pragma unroll
            for (int y = 0; y < 16; ++y) acc += p2[y * KL + j];   // L2-hot
            bn = BcIn[j] + acc;
            if (WRITE_BC && blk == 0) BcOut[j] = bn;
        }
        Bv[j] = bn;
    }
    __syncthreads();

    int k = t >> 5, g = t & 31;
    const float* bk = &Bv[k * L_SZ];
    float m = -3.4e38f;
    for (int l = g; l < s; l += 32) m = fmaxf(m, bk[l]);
    #pragma unroll
    for (int st = 16; st; st >>= 1) m = fmaxf(m, __shfl_xor(m, st, 32));
    float sum = 0.f;
    for (int l = g; l < s; l += 32) sum += __expf(bk[l] - m);
    #pragma unroll
    for (int st = 16; st; st >>= 1) sum += __shfl_xor(sum, st, 32);
    if (g == 0) { mArr[k] = m; rArr[k] = 1.0f / sum; }
    __syncthreads();

    float* dst = Wt + (long)(s - 1) * KL;
    for (int j = t; j < KL; j += 256) {
        int l = j >> 3, kk = j & 7;
        dst[j] = (l < s) ? __expf(Bv[kk * L_SZ + l] - mArr[kk]) * rArr[kk] : 0.f;
    }
}

// ---------------- route: register-resident lc; two-pass phase A; delta
// from registers with 2-row-group scatter rounds.
// grid 4096 x 256.  WRITE_OUT=1 (final iter): write squashed high, stop.
template<int WRITE_OUT>
__global__ __launch_bounds__(256, 5) void k_route8(const float* __restrict__ lc_g,
                                                   const int* __restrict__ seq_len,
                                                   const float* __restrict__ Wt_g,
                                                   const float* __restrict__ S_g,
                                                   const float* __restrict__ St_g,
                                                   float* __restrict__ partial,
                                                   float* __restrict__ out) {
    __shared__ float smem[4608];            // phase A: [0..1599]=Wl,
                                            //          [1600..3647]=hp_part
                                            // delta:   [0..4607] scatter (stride 18)
    __shared__ float hp_s[K_SZ][DK];        // 2 KB (reused as hx)
    __shared__ float hs_s[K_SZ][DK];        // 2 KB
    float* Wl = smem;
    float* hp_part = smem + 1600;           // [4][8][64]

    int t = threadIdx.x;
    int b = blockIdx.x;
    const float4* __restrict__ lc4 =
        (const float4*)(lc_g + (long)b * (L_SZ * DK));
    int sl = seq_len[b];                    // uniform

    // stage W: linear float4 copy (coalesced global, conflict-free LDS)
    {
        const float4* __restrict__ src =
            (const float4*)(Wt_g + (long)(sl - 1) * KL);
        float4* dst = (float4*)Wl;
        for (int j = t; j < KL / 4; j += 256) dst[j] = src[j];
    }
    __syncthreads();

    int grp = t >> 4;                       // row-phase 0..15
    int w = t >> 6;                         // wave

    // ---- load ALL of this thread's lc slice up front (13 loads in flight)
    float4 v[13];
    #pragma unroll
    for (int j = 0; j < 12; ++j) v[j] = lc4[t + 256 * j];
    if (t < 128) v[12] = lc4[t + 3072];
    else         v[12] = make_float4(0.f, 0.f, 0.f, 0.f);

    // ---- Phase A: hp partials, TWO PASSES over k-halves (a[4]: -16 regs)
    #pragma unroll
    for (int half = 0; half < 2; ++half) {
        float4 a[4];
        #pragma unroll
        for (int p = 0; p < 4; ++p) a[p] = make_float4(0.f, 0.f, 0.f, 0.f);
        #pragma unroll
        for (int j = 0; j < 13; ++j) {
            int r = (j == 12) ? ((t < 128) ? 192 + grp : 199) : grp + 16 * j;
            float4 wa = *(const float4*)&Wl[r * 8 + half * 4];  // W[r][4h..4h+3]
            float wk[4] = {wa.x, wa.y, wa.z, wa.w};
            #pragma unroll
            for (int p = 0; p < 4; ++p) {
                a[p].x = fmaf(wk[p], v[j].x, a[p].x);
                a[p].y = fmaf(wk[p], v[j].y, a[p].y);
                a[p].z = fmaf(wk[p], v[j].z, a[p].z);
                a[p].w = fmaf(wk[p], v[j].w, a[p].w);
            }
        }
        // fold 4 in-wave row-groups (butterfly ^16, ^32)
        #pragma unroll
        for (int p = 0; p < 4; ++p) {
            a[p].x += __shfl_xor(a[p].x, 16, 64);
            a[p].y += __shfl_xor(a[p].y, 16, 64);
            a[p].z += __shfl_xor(a[p].z, 16, 64);
            a[p].w += __shfl_xor(a[p].w, 16, 64);
            a[p].x += __shfl_xor(a[p].x, 32, 64);
            a[p].y += __shfl_xor(a[p].y, 32, 64);
            a[p].z += __shfl_xor(a[p].z, 32, 64);
            a[p].w += __shfl_xor(a[p].w, 32, 64);
        }
        if ((t & 63) < 16) {
            int c0 = (t & 15) * 4;
            #pragma unroll
            for (int p = 0; p < 4; ++p)
                *(float4*)&hp_part[w * 512 + (half * 4 + p) * 64 + c0] = a[p];
        }
    }
    __syncthreads();

    // reduce 4 wave-partials -> hp_s
    {
        int kk = t >> 5, ii = (t & 31) * 2;
        float2 r2 = make_float2(0.f, 0.f);
        #pragma unroll
        for (int ww = 0; ww < 4; ++ww) {
            float2 p = *(const float2*)&hp_part[ww * 512 + kk * 64 + ii];
            r2.x += p.x; r2.y += p.y;
        }
        *(float2*)&hp_s[kk][ii] = r2;
    }
    __syncthreads();

    // high[k][o] = sum_i hp[k][i]*S[i][o]; squash.  warp k, o=2g,2g+1
    int k = t >> 5, g = t & 31;
    float h0 = 0.f, h1 = 0.f;
    {
        const float* sp = S_g + 2 * g;
        #pragma unroll 8
        for (int i = 0; i < DK; ++i) {
            float pv = hp_s[k][i];                        // broadcast
            float2 sv = *(const float2*)(sp + i * DK);    // L1-hot, coalesced
            h0 = fmaf(pv, sv.x, h0); h1 = fmaf(pv, sv.y, h1);
        }
        float nn = h0 * h0 + h1 * h1;
        #pragma unroll
        for (int st = 16; st; st >>= 1) nn += __shfl_xor(nn, st, 32);
        float sc = nn / ((1.0f + nn) * sqrtf(nn + 1e-9f));
        h0 *= sc; h1 *= sc;
    }
    if (WRITE_OUT) {
        float2* ob2 = (float2*)(out + (long)b * (K_SZ * DK) + k * DK);
        ob2[g] = make_float2(h0, h1);
        return;                              // uniform early exit
    }
    *(float2*)&hp_s[k][2 * g] = make_float2(h0, h1);  // reuse as hx: same-warp RW

    // hs[k][i] = sum_o high[k][o]*St[o][i]   warp k, i=2g,2g+1
    {
        float s0 = 0.f, s1 = 0.f;
        const float* stp = St_g + 2 * g;
        #pragma unroll 8
        for (int o = 0; o < DK; ++o) {
            float hv = hp_s[k][o];                        // same-warp broadcast
            float2 sv = *(const float2*)(stp + o * DK);   // L1-hot, coalesced
            s0 = fmaf(hv, sv.x, s0); s1 = fmaf(hv, sv.y, s1);
        }
        *(float2*)&hs_s[k][2 * g] = make_float2(s0, s1);
    }
    __syncthreads();

    // ---- delta from registers, 2 row-groups per barrier round (14 barriers).
    //      hs read from LDS per use (b128 broadcast, 2-way banks).
    int c0 = 4 * (t & 15);
    float* pb = partial + (long)b * KL;
    int lane16 = t & 15;
    #pragma unroll
    for (int jb = 0; jb < 6; ++jb) {
        #pragma unroll
        for (int dj = 0; dj < 2; ++dj) {
            int j = 2 * jb + dj;
            #pragma unroll
            for (int kk = 0; kk < 8; ++kk) {
                float4 h = *(const float4*)&hs_s[kk][c0];  // 2-way bcast, free
                float p = v[j].x * h.x + v[j].y * h.y + v[j].z * h.z + v[j].w * h.w;
                smem[((grp + dj * 16) * 8 + kk) * 18 + lane16] = p;  // 2-way
            }
        }
        __syncthreads();
        {
            int s = t >> 3, kk = t & 7;            // s = row slot 0..31
            int r = 32 * jb + s;
            const float2* q = (const float2*)&smem[(s * 8 + kk) * 18];
            float2 q0 = q[0], q1 = q[1], q2 = q[2], q3 = q[3];
            float2 q4 = q[4], q5 = q[5], q6 = q[6], q7 = q[7];
            float sum = ((q0.x + q0.y) + (q1.x + q1.y))
                      + ((q2.x + q2.y) + (q3.x + q3.y))
                      + ((q4.x + q4.y) + (q5.x + q5.y))
                      + ((q6.x + q6.y) + (q7.x + q7.y));
            pb[kk * L_SZ + r] = sum;
        }
        __syncthreads();
    }
    // tail: rows 192..199 (j = 12, held by t<128)
    if (t < 128) {
        #pragma unroll
        for (int kk = 0; kk < 8; ++kk) {
            float4 h = *(const float4*)&hs_s[kk][c0];
            float p = v[12].x * h.x + v[12].y * h.y + v[12].z * h.z + v[12].w * h.w;
            smem[(grp * 8 + kk) * 18 + lane16] = p;
        }
    }
    __syncthreads();
    if (t < 64) {
        int s = t >> 3, kk = t & 7;                // s = 0..7 -> rows 192..199
        int r = 192 + s;
        const float2* q = (const float2*)&smem[(s * 8 + kk) * 18];
        float2 q0 = q[0], q1 = q[1], q2 = q[2], q3 = q[3];
        float2 q4 = q[4], q5 = q[5], q6 = q[6], q7 = q[7];
        float sum = ((q0.x + q0.y) + (q1.x + q1.y))
                  + ((q2.x + q2.y) + (q3.x + q3.y))
                  + ((q4.x + q4.y) + (q5.x + q5.y))
                  + ((q6.x + q6.y) + (q7.x + q7.y));
        pb[kk * L_SZ + r] = sum;
    }
}

// --------------------------- stage-A reduce of partials (unchanged)
__global__ __launch_bounds__(256) void k_reduceA(const float* __restrict__ partial,
                                                 float* __restrict__ partial2) {
    __shared__ float red[256];
    int x = blockIdx.x % 50;
    int y = blockIdx.x / 50;
    int t = threadIdx.x;
    int i = x * 32 + (t & 31);
    int sub = t >> 5;
    float s = 0.f;
    for (int p = y * 256 + sub; p < (y + 1) * 256; p += 8)
        s += partial[(long)p * KL + i];
    red[t] = s;
    __syncthreads();
    for (int step = 4; step >= 1; step >>= 1) {
        if (sub < step) red[t] += red[t + step * 32];
        __syncthreads();
    }
    if (sub == 0) partial2[y * KL + i] = red[t];
}

extern "C" void kernel_launch(void* const* d_in, const int* in_sizes, int n_in,
                              void* d_out, int out_size, void* d_ws, size_t ws_size,
                              hipStream_t stream) {
    const float* lc = (const float*)d_in[0];   // [4096,200,64]
    const int*   sl = (const int*)d_in[1];     // [4096,1]
    const float* Bm = (const float*)d_in[2];   // [1,8,200]
    const float* S  = (const float*)d_in[3];   // [64,64]
    float* out = (float*)d_out;                // [4096,8,64]
    float* ws  = (float*)d_ws;

    float* St      = ws;                       // 4,096
    float* Wt      = St + 4096;                // 320,000  (s,l,k)
    float* Bc      = Wt + 200 * KL;            // 1,600
    float* partial = Bc + KL;                  // 6,553,600
    float* p2      = out;                      // 25,600: overwritten by final pass

    // 8 launches total.
    k_table<1,0><<<201, 256, 0, stream>>>(Bm, S, p2, Bm, Bc, St, Wt);

    k_route8<0><<<B_SZ, 256, 0, stream>>>(lc, sl, Wt, S, St, partial, out);
    k_reduceA  <<<800, 256, 0, stream>>>(partial, p2);
    k_table<0,1><<<200, 256, 0, stream>>>(Bm, S, p2, /*BcIn=*/Bm, /*BcOut=*/Bc, St, Wt);

    k_route8<0><<<B_SZ, 256, 0, stream>>>(lc, sl, Wt, S, St, partial, out);
    k_reduceA  <<<800, 256, 0, stream>>>(partial, p2);
    k_table<0,0><<<200, 256, 0, stream>>>(Bm, S, p2, /*BcIn=*/Bc, /*BcOut=*/Bc, St, Wt);

    k_route8<1><<<B_SZ, 256, 0, stream>>>(lc, sl, Wt, S, St, partial, out);
}

// Round 17
// 278.348 us; speedup vs baseline: 3.1013x; 2.2332x over previous
//
#include <hip/hip_runtime.h>
#include <math.h>

// CapsuleLayer dynamic routing, MI355X.
// B=4096, L=200, Din=Dout=64, K=8, 3 iterations.
//
// R16 -> R17: REVERT to R14 (best: 279us). R15 (cap 85) and R16 (two-pass +
// cap 102) both spilled v[13] to scratch (WRITE_SIZE 58->590/315MB) -- the
// retention design is spill-free only at (256,4): demand ~116 unified regs
// (v[13] lives in AGPRs, invisible in VGPR_Count=64). Retention at occ 40%
// (279us) beats non-retention at occ 60% (R13, 301us): one lc pass saved
// outweighs the occupancy. This is the measured local optimum.
//
// ws layout (floats): St[4096] | Wt[200*1600 (s,l,k)] | Bc[1600] | partial[B*K*L]
// p2[16*1600] lives in d_out (overwritten by the final route pass).

#define B_SZ  4096
#define L_SZ  200
#define DK    64
#define K_SZ  8
#define KL    1600

// ---------------- table kernel: one block per seq-len s = blockIdx+1.
// INIT=1: Bv = Bm; block 200 does the St transpose. INIT=0: Bv = BcIn+sum p2.
template<int INIT, int WRITE_BC>
__global__ __launch_bounds__(256) void k_table(const float* __restrict__ Bm,
                                               const float* __restrict__ S,
                                               const float* __restrict__ p2,
                                               const float* __restrict__ BcIn,
                                               float* __restrict__ BcOut,
                                               float* __restrict__ St,
                                               float* __restrict__ Wt) {
    int t = threadIdx.x;
    int blk = blockIdx.x;
    if (INIT && blk == 200) {          // St[o][i] = S[i][o]
        for (int j = t; j < DK * DK; j += 256) {
            int o = j >> 6, ii = j & 63;
            St[j] = S[ii * DK + o];
        }
        return;
    }
    __shared__ float Bv[KL];           // k-major: Bv[k*200+l]
    __shared__ float mArr[K_SZ], rArr[K_SZ];
    int s = blk + 1;

    for (int j = t; j < KL; j += 256) {
        float bn;
        if (INIT) {
            bn = Bm[j];
        } else {
            float acc = 0.f;
            #pragma unroll
            for (int y = 0; y < 16; ++y) acc += p2[y * KL + j];   // L2-hot
            bn = BcIn[j] + acc;
            if (WRITE_BC && blk == 0) BcOut[j] = bn;
        }
        Bv[j] = bn;
    }
    __syncthreads();

    int k = t >> 5, g = t & 31;
    const float* bk = &Bv[k * L_SZ];
    float m = -3.4e38f;
    for (int l = g; l < s; l += 32) m = fmaxf(m, bk[l]);
    #pragma unroll
    for (int st = 16; st; st >>= 1) m = fmaxf(m, __shfl_xor(m, st, 32));
    float sum = 0.f;
    for (int l = g; l < s; l += 32) sum += __expf(bk[l] - m);
    #pragma unroll
    for (int st = 16; st; st >>= 1) sum += __shfl_xor(sum, st, 32);
    if (g == 0) { mArr[k] = m; rArr[k] = 1.0f / sum; }
    __syncthreads();

    float* dst = Wt + (long)(s - 1) * KL;
    for (int j = t; j < KL; j += 256) {
        int l = j >> 3, kk = j & 7;
        dst[j] = (l < s) ? __expf(Bv[kk * L_SZ + l] - mArr[kk]) * rArr[kk] : 0.f;
    }
}

// ---------------- route: register-resident lc; delta from registers.
// grid 4096 x 256.  WRITE_OUT=1 (final iter): write squashed high, stop.
template<int WRITE_OUT>
__global__ __launch_bounds__(256, 4) void k_route7(const float* __restrict__ lc_g,
                                                   const int* __restrict__ seq_len,
                                                   const float* __restrict__ Wt_g,
                                                   const float* __restrict__ S_g,
                                                   const float* __restrict__ St_g,
                                                   float* __restrict__ partial,
                                                   float* __restrict__ out) {
    __shared__ float smem[3648];            // [0..1599]=Wl, [1600..3647]=hp_part;
                                            // delta scatter reuses [0..2303] (stride 18)
    __shared__ float hp_s[K_SZ][DK];        // 2 KB (reused as hx)
    __shared__ float hs_s[K_SZ][DK];        // 2 KB
    float* Wl = smem;
    float* hp_part = smem + 1600;           // [4][8][64]

    int t = threadIdx.x;
    int b = blockIdx.x;
    const float4* __restrict__ lc4 =
        (const float4*)(lc_g + (long)b * (L_SZ * DK));
    int sl = seq_len[b];                    // uniform

    // stage W: linear float4 copy (coalesced global, conflict-free LDS)
    {
        const float4* __restrict__ src =
            (const float4*)(Wt_g + (long)(sl - 1) * KL);
        float4* dst = (float4*)Wl;
        for (int j = t; j < KL / 4; j += 256) dst[j] = src[j];
    }
    __syncthreads();

    int grp = t >> 4;                       // row-phase 0..15
    int w = t >> 6;                         // wave

    // ---- load ALL of this thread's lc slice up front (13 loads in flight)
    float4 v[13];
    #pragma unroll
    for (int j = 0; j < 12; ++j) v[j] = lc4[t + 256 * j];
    if (t < 128) v[12] = lc4[t + 3072];
    else         v[12] = make_float4(0.f, 0.f, 0.f, 0.f);

    // ---- Phase A: hp partials from registers
    float4 a[8];
    #pragma unroll
    for (int p = 0; p < 8; ++p) a[p] = make_float4(0.f, 0.f, 0.f, 0.f);
    #pragma unroll
    for (int j = 0; j < 13; ++j) {
        int r = (j == 12) ? ((t < 128) ? 192 + grp : 199) : grp + 16 * j;
        float4 wa = *(const float4*)&Wl[r * 8];       // W[r][k=0..3]
        float4 wb = *(const float4*)&Wl[r * 8 + 4];   // W[r][k=4..7]
        float wk[8] = {wa.x, wa.y, wa.z, wa.w, wb.x, wb.y, wb.z, wb.w};
        #pragma unroll
        for (int p = 0; p < 8; ++p) {
            a[p].x = fmaf(wk[p], v[j].x, a[p].x);
            a[p].y = fmaf(wk[p], v[j].y, a[p].y);
            a[p].z = fmaf(wk[p], v[j].z, a[p].z);
            a[p].w = fmaf(wk[p], v[j].w, a[p].w);
        }
    }

    // fold 4 in-wave row-groups (butterfly ^16, ^32)
    #pragma unroll
    for (int p = 0; p < 8; ++p) {
        a[p].x += __shfl_xor(a[p].x, 16, 64);
        a[p].y += __shfl_xor(a[p].y, 16, 64);
        a[p].z += __shfl_xor(a[p].z, 16, 64);
        a[p].w += __shfl_xor(a[p].w, 16, 64);
        a[p].x += __shfl_xor(a[p].x, 32, 64);
        a[p].y += __shfl_xor(a[p].y, 32, 64);
        a[p].z += __shfl_xor(a[p].z, 32, 64);
        a[p].w += __shfl_xor(a[p].w, 32, 64);
    }
    if ((t & 63) < 16) {
        int c0 = (t & 15) * 4;
        #pragma unroll
        for (int p = 0; p < 8; ++p)
            *(float4*)&hp_part[w * 512 + p * 64 + c0] = a[p];
    }
    __syncthreads();

    // reduce 4 wave-partials -> hp_s
    {
        int kk = t >> 5, ii = (t & 31) * 2;
        float2 r2 = make_float2(0.f, 0.f);
        #pragma unroll
        for (int ww = 0; ww < 4; ++ww) {
            float2 p = *(const float2*)&hp_part[ww * 512 + kk * 64 + ii];
            r2.x += p.x; r2.y += p.y;
        }
        *(float2*)&hp_s[kk][ii] = r2;
    }
    __syncthreads();

    // high[k][o] = sum_i hp[k][i]*S[i][o]; squash.  warp k, o=2g,2g+1
    int k = t >> 5, g = t & 31;
    float h0 = 0.f, h1 = 0.f;
    {
        const float* sp = S_g + 2 * g;
        #pragma unroll 8
        for (int i = 0; i < DK; ++i) {
            float pv = hp_s[k][i];                        // broadcast
            float2 sv = *(const float2*)(sp + i * DK);    // L1-hot, coalesced
            h0 = fmaf(pv, sv.x, h0); h1 = fmaf(pv, sv.y, h1);
        }
        float nn = h0 * h0 + h1 * h1;
        #pragma unroll
        for (int st = 16; st; st >>= 1) nn += __shfl_xor(nn, st, 32);
        float sc = nn / ((1.0f + nn) * sqrtf(nn + 1e-9f));
        h0 *= sc; h1 *= sc;
    }
    if (WRITE_OUT) {
        float2* ob2 = (float2*)(out + (long)b * (K_SZ * DK) + k * DK);
        ob2[g] = make_float2(h0, h1);
        return;                              // uniform early exit
    }
    *(float2*)&hp_s[k][2 * g] = make_float2(h0, h1);  // reuse as hx: same-warp RW

    // hs[k][i] = sum_o high[k][o]*St[o][i]   warp k, i=2g,2g+1
    {
        float s0 = 0.f, s1 = 0.f;
        const float* stp = St_g + 2 * g;
        #pragma unroll 8
        for (int o = 0; o < DK; ++o) {
            float hv = hp_s[k][o];                        // same-warp broadcast
            float2 sv = *(const float2*)(stp + o * DK);   // L1-hot, coalesced
            s0 = fmaf(hv, sv.x, s0); s1 = fmaf(hv, sv.y, s1);
        }
        *(float2*)&hs_s[k][2 * g] = make_float2(s0, s1);
    }
    __syncthreads();

    // ---- delta from registers: thread t holds rows grp+16j, cols c0..c0+3.
    float4 hs4[8];
    int c0 = 4 * (t & 15);
    #pragma unroll
    for (int kk = 0; kk < 8; ++kk)
        hs4[kk] = *(const float4*)&hs_s[kk][c0];   // 2-way broadcast, free

    float* pb = partial + (long)b * KL;
    int lane16 = t & 15;
    #pragma unroll
    for (int j = 0; j < 13; ++j) {
        if (j < 12 || t < 128) {                   // valid rows only
            #pragma unroll
            for (int kk = 0; kk < 8; ++kk) {
                float4 h = hs4[kk];
                float p = v[j].x * h.x + v[j].y * h.y + v[j].z * h.z + v[j].w * h.w;
                smem[(grp * 8 + kk) * 18 + lane16] = p;   // <=2-way banks
            }
        }
        __syncthreads();
        int nOut = (j < 12) ? 128 : 64;
        if (t < nOut) {
            int s = t >> 3, kk = t & 7;            // s = row slot
            int r = 16 * j + s;
            const float2* q = (const float2*)&smem[(s * 8 + kk) * 18];
            float2 q0 = q[0], q1 = q[1], q2 = q[2], q3 = q[3];
            float2 q4 = q[4], q5 = q[5], q6 = q[6], q7 = q[7];
            float sum = ((q0.x + q0.y) + (q1.x + q1.y))
                      + ((q2.x + q2.y) + (q3.x + q3.y))
                      + ((q4.x + q4.y) + (q5.x + q5.y))
                      + ((q6.x + q6.y) + (q7.x + q7.y));
            pb[kk * L_SZ + r] = sum;
        }
        __syncthreads();
    }
}

// --------------------------- stage-A reduce of partials (unchanged)
__global__ __launch_bounds__(256) void k_reduceA(const float* __restrict__ partial,
                                                 float* __restrict__ partial2) {
    __shared__ float red[256];
    int x = blockIdx.x % 50;
    int y = blockIdx.x / 50;
    int t = threadIdx.x;
    int i = x * 32 + (t & 31);
    int sub = t >> 5;
    float s = 0.f;
    for (int p = y * 256 + sub; p < (y + 1) * 256; p += 8)
        s += partial[(long)p * KL + i];
    red[t] = s;
    __syncthreads();
    for (int step = 4; step >= 1; step >>= 1) {
        if (sub < step) red[t] += red[t + step * 32];
        __syncthreads();
    }
    if (sub == 0) partial2[y * KL + i] = red[t];
}

extern "C" void kernel_launch(void* const* d_in, const int* in_sizes, int n_in,
                              void* d_out, int out_size, void* d_ws, size_t ws_size,
                              hipStream_t stream) {
    const float* lc = (const float*)d_in[0];   // [4096,200,64]
    const int*   sl = (const int*)d_in[1];     // [4096,1]
    const float* Bm = (const float*)d_in[2];   // [1,8,200]
    const float* S  = (const float*)d_in[3];   // [64,64]
    float* out = (float*)d_out;                // [4096,8,64]
    float* ws  = (float*)d_ws;

    float* St      = ws;                       // 4,096
    float* Wt      = St + 4096;                // 320,000  (s,l,k)
    float* Bc      = Wt + 200 * KL;            // 1,600
    float* partial = Bc + KL;                  // 6,553,600
    float* p2      = out;                      // 25,600: overwritten by final pass

    // 8 launches total.
    k_table<1,0><<<201, 256, 0, stream>>>(Bm, S, p2, Bm, Bc, St, Wt);

    k_route7<0><<<B_SZ, 256, 0, stream>>>(lc, sl, Wt, S, St, partial, out);
    k_reduceA  <<<800, 256, 0, stream>>>(partial, p2);
    k_table<0,1><<<200, 256, 0, stream>>>(Bm, S, p2, /*BcIn=*/Bm, /*BcOut=*/Bc, St, Wt);

    k_route7<0><<<B_SZ, 256, 0, stream>>>(lc, sl, Wt, S, St, partial, out);
    k_reduceA  <<<800, 256, 0, stream>>>(partial, p2);
    k_table<0,0><<<200, 256, 0, stream>>>(Bm, S, p2, /*BcIn=*/Bc, /*BcOut=*/Bc, St, Wt);

    k_route7<1><<<B_SZ, 256, 0, stream>>>(lc, sl, Wt, S, St, partial, out);
}